// Round 3
// baseline (424.514 us; speedup 1.0000x reference)
//
#include <hip/hip_runtime.h>

#define COLS 16384
#define TPB  256
#define CHUNK 8                                   // f32 elems per chunk (2x16B load/store)
#define CHUNKS_PER_ROW    (COLS / CHUNK)          // 2048
#define CHUNKS_PER_THREAD (CHUNKS_PER_ROW / TPB)  // 8
#define LDSPAD(i) ((i) + ((i) >> 3))              // +1 float pad per 8 sums

__global__ __launch_bounds__(TPB) void revcumsum_rows(const float* __restrict__ x,
                                                      float* __restrict__ out) {
    __shared__ float s_sums[CHUNKS_PER_ROW + (CHUNKS_PER_ROW >> 3)]; // 2304 floats
    __shared__ float s_wt[TPB / 64];

    const int t = threadIdx.x;
    const long long row = blockIdx.x;
    const float* __restrict__ rowp = x   + row * (long long)COLS;
    float* __restrict__       outp = out + row * (long long)COLS;

    // ---- Phase A: coalesced 2x16B loads per chunk, keep in regs, chunk sums to LDS.
    float4 raw[CHUNKS_PER_THREAD][2];
    #pragma unroll
    for (int i = 0; i < CHUNKS_PER_THREAD; ++i) {
        const int c = i * TPB + t;
        raw[i][0] = *reinterpret_cast<const float4*>(rowp + (size_t)c * CHUNK);
        raw[i][1] = *reinterpret_cast<const float4*>(rowp + (size_t)c * CHUNK + 4);
        const float s0 = (raw[i][0].x + raw[i][0].y) + (raw[i][0].z + raw[i][0].w);
        const float s1 = (raw[i][1].x + raw[i][1].y) + (raw[i][1].z + raw[i][1].w);
        s_sums[LDSPAD(c)] = s0 + s1;
    }
    __syncthreads();

    // ---- Phase B: thread t owns contiguous chunks [8t, 8t+8).
    float segv[CHUNKS_PER_THREAD];
    float T = 0.f;
    #pragma unroll
    for (int j = 0; j < CHUNKS_PER_THREAD; ++j) {
        segv[j] = s_sums[LDSPAD(t * CHUNKS_PER_THREAD + j)];
        T += segv[j];
    }
    // Wave-level inclusive SUFFIX scan across 64 lanes.
    const int lane = t & 63;
    const int w    = t >> 6;
    float s = T;
    #pragma unroll
    for (int d = 1; d < 64; d <<= 1) {
        float o = __shfl_down(s, d);
        if (lane + d < 64) s += o;
    }
    if (lane == 0) s_wt[w] = s;   // lane 0's inclusive suffix == wave total
    __syncthreads();
    float wave_off = 0.f;
    #pragma unroll
    for (int w2 = 0; w2 < TPB / 64; ++w2)
        if (w2 > w) wave_off += s_wt[w2];
    // Exclusive suffix across all threads (= everything owned by threads > t).
    float running = (s - T) + wave_off;

    // Per-chunk exclusive suffixes written back in place.
    #pragma unroll
    for (int j = CHUNKS_PER_THREAD - 1; j >= 0; --j) {
        const int idx = LDSPAD(t * CHUNKS_PER_THREAD + j);
        const float v = segv[j];
        s_sums[idx] = running;
        running += v;
    }
    __syncthreads();

    // ---- Phase C: in-register reverse cumsum per chunk, 2x16B f32 stores.
    #pragma unroll
    for (int i = 0; i < CHUNKS_PER_THREAD; ++i) {
        const int c = i * TPB + t;
        const float off = s_sums[LDSPAD(c)];
        float f[CHUNK];
        f[0] = raw[i][0].x; f[1] = raw[i][0].y; f[2] = raw[i][0].z; f[3] = raw[i][0].w;
        f[4] = raw[i][1].x; f[5] = raw[i][1].y; f[6] = raw[i][1].z; f[7] = raw[i][1].w;
        float acc = off;
        float o[CHUNK];
        #pragma unroll
        for (int j = CHUNK - 1; j >= 0; --j) {
            acc += f[j];
            o[j] = acc;
        }
        float4 o0 = make_float4(o[0], o[1], o[2], o[3]);
        float4 o1 = make_float4(o[4], o[5], o[6], o[7]);
        *reinterpret_cast<float4*>(outp + (size_t)c * CHUNK)     = o0;
        *reinterpret_cast<float4*>(outp + (size_t)c * CHUNK + 4) = o1;
    }
}

extern "C" void kernel_launch(void* const* d_in, const int* in_sizes, int n_in,
                              void* d_out, int out_size, void* d_ws, size_t ws_size,
                              hipStream_t stream) {
    const float* x = (const float*)d_in[0];
    float* out = (float*)d_out;
    const int rows = in_sizes[0] / COLS;   // 16384
    revcumsum_rows<<<rows, TPB, 0, stream>>>(x, out);
}

// Round 4
// 394.722 us; speedup vs baseline: 1.0755x; 1.0755x over previous
//
#include <hip/hip_runtime.h>

#define COLS 16384
#define TPB  1024
#define CHUNK 8                                   // f32 elems per chunk
#define CPR  (COLS / CHUNK)                       // 2048 chunks per row
#define CPT  (CPR / TPB)                          // 2 chunks per thread
#define NW   (TPB / 64)                           // 16 waves
#define LDSPAD(i) ((i) + ((i) >> 3))              // +1 float pad per 8 sums

__global__ __launch_bounds__(TPB) void revcumsum_rows(const float* __restrict__ x,
                                                      float* __restrict__ out) {
    // Row data lives in LDS, not registers: 64KB + 9.2KB -> 2 blocks/CU, 32 waves/CU.
    __shared__ float4 s_data[2][CPR];               // [half][chunk], 65536 B
    __shared__ float  s_suf[CPR + (CPR >> 3)];      // 9216 B, padded chunk sums/suffixes
    __shared__ float  s_wt[NW];                     // wave totals

    const int t = threadIdx.x;
    const long long row = blockIdx.x;
    const float4* __restrict__ rowp4 = reinterpret_cast<const float4*>(x + row * (long long)COLS);
    float4* __restrict__       outp4 = reinterpret_cast<float4*>(out + row * (long long)COLS);

    // ---- Phase A: load row -> LDS, per-chunk sums.
    #pragma unroll
    for (int k = 0; k < CPT; ++k) {
        const int c = k * TPB + t;
        const float4 a = rowp4[2 * c];
        const float4 b = rowp4[2 * c + 1];
        s_data[0][c] = a;                           // byte 16*c: lane-consecutive, conflict-free
        s_data[1][c] = b;
        const float s0 = (a.x + a.y) + (a.z + a.w);
        const float s1 = (b.x + b.y) + (b.z + b.w);
        s_suf[LDSPAD(c)] = s0 + s1;
    }
    __syncthreads();

    // ---- Phase B: thread t owns contiguous chunks [2t, 2t+2).
    float segv[CPT];
    float T = 0.f;
    #pragma unroll
    for (int j = 0; j < CPT; ++j) {
        segv[j] = s_suf[LDSPAD(CPT * t + j)];
        T += segv[j];
    }
    // Wave-level inclusive SUFFIX scan across 64 lanes.
    const int lane = t & 63;
    const int w    = t >> 6;
    float s = T;
    #pragma unroll
    for (int d = 1; d < 64; d <<= 1) {
        float o = __shfl_down(s, d);
        if (lane + d < 64) s += o;
    }
    if (lane == 0) s_wt[w] = s;                     // lane 0's inclusive suffix == wave total
    __syncthreads();
    float wave_off = 0.f;
    #pragma unroll
    for (int w2 = 0; w2 < NW; ++w2)
        if (w2 > w) wave_off += s_wt[w2];           // same-address reads -> broadcast
    // Exclusive suffix across all threads (= everything owned by threads > t).
    float running = (s - T) + wave_off;

    // Per-chunk exclusive suffixes written back in place.
    #pragma unroll
    for (int j = CPT - 1; j >= 0; --j) {
        const int idx = LDSPAD(CPT * t + j);
        const float v = segv[j];
        s_suf[idx] = running;
        running += v;
    }
    __syncthreads();

    // ---- Phase C: read row back from LDS, in-register reverse cumsum, store.
    #pragma unroll
    for (int k = 0; k < CPT; ++k) {
        const int c = k * TPB + t;
        const float4 a = s_data[0][c];
        const float4 b = s_data[1][c];
        const float off = s_suf[LDSPAD(c)];
        float f[CHUNK] = {a.x, a.y, a.z, a.w, b.x, b.y, b.z, b.w};
        float acc = off;
        float o[CHUNK];
        #pragma unroll
        for (int j = CHUNK - 1; j >= 0; --j) {
            acc += f[j];
            o[j] = acc;
        }
        outp4[2 * c]     = make_float4(o[0], o[1], o[2], o[3]);
        outp4[2 * c + 1] = make_float4(o[4], o[5], o[6], o[7]);
    }
}

extern "C" void kernel_launch(void* const* d_in, const int* in_sizes, int n_in,
                              void* d_out, int out_size, void* d_ws, size_t ws_size,
                              hipStream_t stream) {
    const float* x = (const float*)d_in[0];
    float* out = (float*)d_out;
    const int rows = in_sizes[0] / COLS;   // 16384
    revcumsum_rows<<<rows, TPB, 0, stream>>>(x, out);
}